// Round 4
// baseline (184.778 us; speedup 1.0000x reference)
//
#include <hip/hip_runtime.h>
#include <math.h>

#define TS  1024   // k_stats threads
#define NBS 512    // k_stats blocks (records)
#define TL  512    // k_loss threads
#define NBL 1024   // k_loss blocks

// ---- monotone float <-> uint encoding (order-preserving) ----
__device__ __forceinline__ unsigned enc_f(float f) {
    unsigned b = __float_as_uint(f);
    return (b & 0x80000000u) ? ~b : (b | 0x80000000u);
}
__device__ __forceinline__ float dec_f(unsigned u) {
    unsigned b = (u & 0x80000000u) ? (u ^ 0x80000000u) : ~u;
    return __uint_as_float(b);
}
#define ENC_NEG_INF 0x007FFFFFu   // enc(-inf): identity for max
#define ENC_POS_INF 0xFF800000u   // enc(+inf): identity for min
// word w in a 32-word record: [0..7] gmax(max) [8..15] pmin(min) [16..23] zmin(min) [24..31] zmax(max)
__device__ __forceinline__ unsigned ident_w(int w) {
    return (w < 8 || w >= 24) ? ENC_NEG_INF : ENC_POS_INF;
}

// ws layout (unsigned words):
//   [32..33] double acc   [35] done2   [40..47] mu[8] (float bits)
//   [64 + blk*32 + w]     per-block stat records (NBS blocks)
//   [ZOFF_W ..]           staged z, N floats      (byte offset 4 MB)
//   [SOFF_W ..]           staged seg, 1 B/point   (byte offset 32 MB)
// All cross-kernel data crosses a kernel boundary -> plain loads/stores are coherent.
#define SLOT(base, blk) ((base) + 64 + (blk) * 32)
#define ZOFF_W (1u << 20)
#define SOFF_W (8u << 20)

#define CNT_B(ii, bdst) do { bdst = 0; \
    _Pragma("unroll") for (int j_ = 0; j_ < 8; ++j_) bdst += ((ii) >= roff[j_]); } while (0)

#define FLUSH_LDS(bb, g_, p_, mn_, mx_) do { \
    atomicMax(&s_stats[      (bb)], enc_f(g_));  \
    atomicMin(&s_stats[ 8  + (bb)], enc_f(p_));  \
    atomicMin(&s_stats[16  + (bb)], enc_f(mn_)); \
    atomicMax(&s_stats[24  + (bb)], enc_f(mx_)); } while (0)

__device__ __forceinline__ float point_loss(float p0, float p1, int s, float z, float mu) {
    float m   = fmaxf(p0, p1);
    float lse = m + logf(expf(p0 - m) + expf(p1 - m));
    float lpt = ((s == 0) ? p0 : p1) - lse;
    float pt  = expf(lpt);
    float om  = 1.0f - pt;
    float loss = -lpt * om * om;           // LOSS_WEIGHT=ALPHA=1, GAMMA=2
    float d  = z - mu;
    float cf = (z <= mu) ? 50.0f : 3.125f; // 1/(2*0.1^2), 1/(2*0.4^2)
    float w  = expf(-d * d * cf);
    if (z > mu && d > 0.8f) w = 0.1f;      // d > 2*0.4 -> MIN_VAL
    return loss * w;
}

// Pass 1: stats over (z, segment) with float4/int4 vector loads; stages compact
// z (f32) + seg (1 byte) into ws so pass 2 never re-reads coord/segment.
__global__ __launch_bounds__(TS, 8) void k_stats(
        const float* __restrict__ coord, const int* __restrict__ segment,
        const int* __restrict__ offset, unsigned* __restrict__ ws, int n, int nb) {
    __shared__ unsigned s_stats[32];
    const int tid = threadIdx.x;
    if (tid < 32) s_stats[tid] = ident_w(tid);
    int roff[8];
    #pragma unroll
    for (int j = 0; j < 8; ++j) roff[j] = (j < nb) ? offset[j] : 0x7FFFFFFF;
    __syncthreads();

    int chunk = (n + (int)gridDim.x - 1) / (int)gridDim.x;
    chunk = (chunk + 3) & ~3;                       // keep 4-point alignment
    const int start = blockIdx.x * chunk;
    const int end   = min(n, start + chunk);

    float*         zs = (float*)(ws + ZOFF_W);
    unsigned char* sb = (unsigned char*)(ws + SOFF_W);

    if (start < end) {
        int ba = 0, bb = 0;
        #pragma unroll
        for (int j = 0; j < 8; ++j) { ba += (start >= roff[j]); bb += ((end - 1) >= roff[j]); }
        float lg = -INFINITY, lp = INFINITY, lmn = INFINITY, lmx = -INFINITY;

        if (ba == bb && ((end - start) % (4 * TS) == 0)) {
            // fast path: one cloud, full 4-pt tiles; 16B vector loads throughout
            const float4* c4 = (const float4*)coord;
            const int4*   s4 = (const int4*)segment;
            float4*       z4 = (float4*)zs;
            unsigned*     sw = (unsigned*)sb;
            for (int p0 = start; p0 < end; p0 += 4 * TS) {
                const int q = (p0 >> 2) + tid;      // 4-pt group index
                float4 a = c4[3 * q + 0];           // x0 y0 z0 x1
                float4 b = c4[3 * q + 1];           // y1 z1 x2 y2
                float4 c = c4[3 * q + 2];           // z2 x3 y3 z3
                int4   s = s4[q];
                const float z0 = a.z, z1 = b.y, z2 = c.x, z3 = c.w;
                z4[q] = make_float4(z0, z1, z2, z3);
                sw[q] = (unsigned)(s.x & 1) | ((unsigned)(s.y & 1) << 8)
                      | ((unsigned)(s.z & 1) << 16) | ((unsigned)(s.w & 1) << 24);
                lmn = fminf(lmn, fminf(fminf(z0, z1), fminf(z2, z3)));
                lmx = fmaxf(lmx, fmaxf(fmaxf(z0, z1), fmaxf(z2, z3)));
                lg = fmaxf(lg, (s.x == 0) ? z0 : -INFINITY);
                lg = fmaxf(lg, (s.y == 0) ? z1 : -INFINITY);
                lg = fmaxf(lg, (s.z == 0) ? z2 : -INFINITY);
                lg = fmaxf(lg, (s.w == 0) ? z3 : -INFINITY);
                lp = fminf(lp, (s.x != 0) ? z0 : INFINITY);
                lp = fminf(lp, (s.y != 0) ? z1 : INFINITY);
                lp = fminf(lp, (s.z != 0) ? z2 : INFINITY);
                lp = fminf(lp, (s.w != 0) ? z3 : INFINITY);
            }
            #pragma unroll
            for (int m = 32; m; m >>= 1) {
                lg  = fmaxf(lg,  __shfl_xor(lg,  m, 64));
                lp  = fminf(lp,  __shfl_xor(lp,  m, 64));
                lmn = fminf(lmn, __shfl_xor(lmn, m, 64));
                lmx = fmaxf(lmx, __shfl_xor(lmx, m, 64));
            }
            if ((tid & 63) == 0) FLUSH_LDS(ba, lg, lp, lmn, lmx);
        } else {
            // slow path (boundary/partial blocks): scalar, per-point batch tracking
            int curb = -1;
            for (int i = start + tid; i < end; i += TS) {
                float z = coord[3 * i + 2]; int s = segment[i], b;
                zs[i] = z;
                sb[i] = (unsigned char)(s & 1);
                CNT_B(i, b);
                if (b != curb) {
                    if (curb >= 0) FLUSH_LDS(curb, lg, lp, lmn, lmx);
                    lg = -INFINITY; lp = INFINITY; lmn = INFINITY; lmx = -INFINITY;
                    curb = b;
                }
                lmn = fminf(lmn, z); lmx = fmaxf(lmx, z);
                if (s == 0) lg = fmaxf(lg, z); else lp = fminf(lp, z);
            }
            if (curb >= 0) FLUSH_LDS(curb, lg, lp, lmn, lmx);
        }
    }
    __syncthreads();
    if (tid < 32) SLOT(ws, blockIdx.x)[tid] = s_stats[tid];   // kernel boundary = coherence
}

// Tiny pass: combine NBS records -> mu[8]; init accumulator + done counter.
__global__ __launch_bounds__(256) void k_mu(unsigned* __restrict__ ws) {
    __shared__ unsigned s_comb[32];
    const int tid = threadIdx.x;
    if (tid < 32) s_comb[tid] = ident_w(tid);
    __syncthreads();
    const int w = tid & 31, g = tid >> 5;            // 8 groups x 32 words
    unsigned v = ident_w(w);
    for (int j = g; j < NBS; j += 8) {
        unsigned u = SLOT((const unsigned*)ws, j)[w];
        v = (w < 8 || w >= 24) ? max(v, u) : min(v, u);
    }
    if (w < 8 || w >= 24) atomicMax(&s_comb[w], v);
    else                  atomicMin(&s_comb[w], v);
    __syncthreads();
    if (tid < 8) {
        unsigned ug = s_comb[tid], up = s_comb[8 + tid];
        float gv = dec_f(ug), pv = dec_f(up);
        if (ug == ENC_NEG_INF) gv = dec_f(s_comb[16 + tid]);  // no ground -> z.min
        if (up == ENC_POS_INF) pv = dec_f(s_comb[24 + tid]);  // no plant  -> z.max
        ws[40 + tid] = __float_as_uint(gv + (pv - gv) * 0.5f);
    }
    if (tid == 64) { *(double*)(ws + 32) = 0.0; ws[35] = 0u; }
}

// Pass 2: loss from pred (float4) + staged z (float4) + staged seg (u32/4pts).
__global__ __launch_bounds__(TL, 8) void k_loss(
        const float* __restrict__ pred, const int* __restrict__ offset,
        unsigned* __restrict__ ws, float* __restrict__ out, int n, int nb) {
    __shared__ float s_mu[8];
    __shared__ float s_part[TL / 64];
    const int tid = threadIdx.x;
    int roff[8];
    #pragma unroll
    for (int j = 0; j < 8; ++j) roff[j] = (j < nb) ? offset[j] : 0x7FFFFFFF;
    if (tid < 8) s_mu[tid] = __uint_as_float(ws[40 + tid]);
    __syncthreads();

    int chunk = (n + (int)gridDim.x - 1) / (int)gridDim.x;
    chunk = (chunk + 3) & ~3;
    const int start = blockIdx.x * chunk;
    const int end   = min(n, start + chunk);

    const float*         zs  = (const float*)(ws + ZOFF_W);
    const unsigned char* sbB = (const unsigned char*)(ws + SOFF_W);

    float lsum = 0.0f;
    if (start < end) {
        int ba = 0, bb = 0;
        #pragma unroll
        for (int j = 0; j < 8; ++j) { ba += (start >= roff[j]); bb += ((end - 1) >= roff[j]); }

        if (ba == bb && ((end - start) % (4 * TL) == 0)) {
            const float mu = s_mu[ba];
            const float4*   p4 = (const float4*)pred;
            const float4*   z4 = (const float4*)zs;
            const unsigned* sw = (const unsigned*)sbB;
            for (int p0 = start; p0 < end; p0 += 4 * TL) {
                const int q = (p0 >> 2) + tid;       // 4-pt group index
                float4 pa = p4[2 * q + 0];           // p0x p0y p1x p1y
                float4 pb = p4[2 * q + 1];           // p2x p2y p3x p3y
                float4 zz = z4[q];
                unsigned s = sw[q];
                lsum += point_loss(pa.x, pa.y, (int)( s        & 1u), zz.x, mu);
                lsum += point_loss(pa.z, pa.w, (int)((s >>  8) & 1u), zz.y, mu);
                lsum += point_loss(pb.x, pb.y, (int)((s >> 16) & 1u), zz.z, mu);
                lsum += point_loss(pb.z, pb.w, (int)((s >> 24) & 1u), zz.w, mu);
            }
        } else {
            const float2* pred2 = (const float2*)pred;
            for (int i = start + tid; i < end; i += TL) {
                int b; CNT_B(i, b);
                float2 pp = pred2[i];
                lsum += point_loss(pp.x, pp.y, (int)sbB[i], zs[i], s_mu[b]);
            }
        }
    }

    #pragma unroll
    for (int off = 32; off > 0; off >>= 1) lsum += __shfl_down(lsum, off, 64);
    if ((tid & 63) == 0) s_part[tid >> 6] = lsum;
    __syncthreads();
    if (tid == 0) {
        float t = 0.0f;
        #pragma unroll
        for (int wv = 0; wv < TL / 64; ++wv) t += s_part[wv];
        double* acc = (double*)(ws + 32);
        atomicAdd(acc, (double)t);
        __threadfence();
        unsigned c = atomicAdd(&ws[35], 1u);
        if (c == (unsigned)gridDim.x - 1u) {       // last block finalizes
            double v = atomicAdd(acc, 0.0);        // coherent read via atomic
            out[0] = (float)(v / (double)n);
        }
    }
}

extern "C" void kernel_launch(void* const* d_in, const int* in_sizes, int n_in,
                              void* d_out, int out_size, void* d_ws, size_t ws_size,
                              hipStream_t stream) {
    const float* pred    = (const float*)d_in[0];
    const float* coord   = (const float*)d_in[1];
    const int*   segment = (const int*)d_in[2];
    const int*   offset  = (const int*)d_in[3];
    const int n  = in_sizes[2];
    const int nb = in_sizes[3];
    unsigned* ws = (unsigned*)d_ws;

    hipLaunchKernelGGL(k_stats, dim3(NBS), dim3(TS), 0, stream,
                       coord, segment, offset, ws, n, nb);
    hipLaunchKernelGGL(k_mu, dim3(1), dim3(256), 0, stream, ws);
    hipLaunchKernelGGL(k_loss, dim3(NBL), dim3(TL), 0, stream,
                       pred, offset, ws, (float*)d_out, n, nb);
}

// Round 5
// 133.342 us; speedup vs baseline: 1.3857x; 1.3857x over previous
//
#include <hip/hip_runtime.h>
#include <math.h>

#define T   1024   // threads per block (16 waves)
#define NB  512    // blocks for k_stats / k_loss (2 blocks/CU -> 32 waves/CU)

// ---- monotone float <-> uint encoding (order-preserving) ----
__device__ __forceinline__ unsigned enc_f(float f) {
    unsigned b = __float_as_uint(f);
    return (b & 0x80000000u) ? ~b : (b | 0x80000000u);
}
__device__ __forceinline__ float dec_f(unsigned u) {
    unsigned b = (u & 0x80000000u) ? (u ^ 0x80000000u) : ~u;
    return __uint_as_float(b);
}
#define ENC_NEG_INF 0x007FFFFFu   // enc(-inf): identity for max
#define ENC_POS_INF 0xFF800000u   // enc(+inf): identity for min
// word w in a 32-word record: [0..7] gmax(max) [8..15] pmin(min) [16..23] zmin(min) [24..31] zmax(max)
__device__ __forceinline__ unsigned ident_w(int w) {
    return (w < 8 || w >= 24) ? ENC_NEG_INF : ENC_POS_INF;
}

// ws layout (unsigned words) — NO contended atomics anywhere; all cross-kernel
// data crosses a kernel boundary (plain loads/stores, coherent at dispatch edges):
//   [64 + blk*32 + w]   per-block stat records, NB blocks      (k_stats -> k_loss)
//   [PART_W + blk]      per-block float partial sums, NB blocks (k_loss -> k_final)
//   [ZOFF_W ..]         staged z, N floats   (byte offset 4 MB) (k_stats -> k_loss)
//   [SOFF_W ..]         staged seg, 1 B/pt   (byte offset 32 MB)(k_stats -> k_loss)
#define SLOT(base, blk) ((base) + 64 + (blk) * 32)
#define PART_W  20000u
#define ZOFF_W (1u << 20)
#define SOFF_W (8u << 20)

#define CNT_B(ii, bdst) do { bdst = 0; \
    _Pragma("unroll") for (int j_ = 0; j_ < 8; ++j_) bdst += ((ii) >= roff[j_]); } while (0)

#define FLUSH_LDS(bb, g_, p_, mn_, mx_) do { \
    atomicMax(&s_stats[      (bb)], enc_f(g_));  \
    atomicMin(&s_stats[ 8  + (bb)], enc_f(p_));  \
    atomicMin(&s_stats[16  + (bb)], enc_f(mn_)); \
    atomicMax(&s_stats[24  + (bb)], enc_f(mx_)); } while (0)

__device__ __forceinline__ float point_loss(float p0, float p1, int s, float z, float mu) {
    float m   = fmaxf(p0, p1);
    float lse = m + logf(expf(p0 - m) + expf(p1 - m));
    float lpt = ((s == 0) ? p0 : p1) - lse;
    float pt  = expf(lpt);
    float om  = 1.0f - pt;
    float loss = -lpt * om * om;           // LOSS_WEIGHT=ALPHA=1, GAMMA=2
    float d  = z - mu;
    float cf = (z <= mu) ? 50.0f : 3.125f; // 1/(2*0.1^2), 1/(2*0.4^2)
    float w  = expf(-d * d * cf);
    if (z > mu && d > 0.8f) w = 0.1f;      // d > 2*0.4 -> MIN_VAL
    return loss * w;
}

// Pass 1: stats over (z, segment) with float4/int4 loads; stages compact
// z (f32) + seg (1 byte) into ws so pass 2 never re-reads coord/segment.
// Ends with plain stores only (records) — no atomics, no fences.
__global__ __launch_bounds__(T, 8) void k_stats(
        const float* __restrict__ coord, const int* __restrict__ segment,
        const int* __restrict__ offset, unsigned* __restrict__ ws, int n, int nb) {
    __shared__ unsigned s_stats[32];
    const int tid = threadIdx.x;
    if (tid < 32) s_stats[tid] = ident_w(tid);
    int roff[8];
    #pragma unroll
    for (int j = 0; j < 8; ++j) roff[j] = (j < nb) ? offset[j] : 0x7FFFFFFF;
    __syncthreads();

    int chunk = (n + (int)gridDim.x - 1) / (int)gridDim.x;
    chunk = (chunk + 3) & ~3;                       // keep 4-point alignment
    const int start = blockIdx.x * chunk;
    const int end   = min(n, start + chunk);

    float*         zs = (float*)(ws + ZOFF_W);
    unsigned char* sb = (unsigned char*)(ws + SOFF_W);

    if (start < end) {
        int ba = 0, bb = 0;
        #pragma unroll
        for (int j = 0; j < 8; ++j) { ba += (start >= roff[j]); bb += ((end - 1) >= roff[j]); }
        float lg = -INFINITY, lp = INFINITY, lmn = INFINITY, lmx = -INFINITY;

        if (ba == bb && ((end - start) % (4 * T) == 0)) {
            // fast path: one cloud, full 4-pt tiles; 16B vector loads throughout
            const float4* c4 = (const float4*)coord;
            const int4*   s4 = (const int4*)segment;
            float4*       z4 = (float4*)zs;
            unsigned*     sw = (unsigned*)sb;
            for (int p0 = start; p0 < end; p0 += 4 * T) {
                const int q = (p0 >> 2) + tid;      // 4-pt group index
                float4 a = c4[3 * q + 0];           // x0 y0 z0 x1
                float4 b = c4[3 * q + 1];           // y1 z1 x2 y2
                float4 c = c4[3 * q + 2];           // z2 x3 y3 z3
                int4   s = s4[q];
                const float z0 = a.z, z1 = b.y, z2 = c.x, z3 = c.w;
                z4[q] = make_float4(z0, z1, z2, z3);
                sw[q] = (unsigned)(s.x & 1) | ((unsigned)(s.y & 1) << 8)
                      | ((unsigned)(s.z & 1) << 16) | ((unsigned)(s.w & 1) << 24);
                lmn = fminf(lmn, fminf(fminf(z0, z1), fminf(z2, z3)));
                lmx = fmaxf(lmx, fmaxf(fmaxf(z0, z1), fmaxf(z2, z3)));
                lg = fmaxf(lg, (s.x == 0) ? z0 : -INFINITY);
                lg = fmaxf(lg, (s.y == 0) ? z1 : -INFINITY);
                lg = fmaxf(lg, (s.z == 0) ? z2 : -INFINITY);
                lg = fmaxf(lg, (s.w == 0) ? z3 : -INFINITY);
                lp = fminf(lp, (s.x != 0) ? z0 : INFINITY);
                lp = fminf(lp, (s.y != 0) ? z1 : INFINITY);
                lp = fminf(lp, (s.z != 0) ? z2 : INFINITY);
                lp = fminf(lp, (s.w != 0) ? z3 : INFINITY);
            }
            #pragma unroll
            for (int m = 32; m; m >>= 1) {
                lg  = fmaxf(lg,  __shfl_xor(lg,  m, 64));
                lp  = fminf(lp,  __shfl_xor(lp,  m, 64));
                lmn = fminf(lmn, __shfl_xor(lmn, m, 64));
                lmx = fmaxf(lmx, __shfl_xor(lmx, m, 64));
            }
            if ((tid & 63) == 0) FLUSH_LDS(ba, lg, lp, lmn, lmx);
        } else {
            // slow path (boundary/partial blocks): scalar, per-point batch tracking
            int curb = -1;
            for (int i = start + tid; i < end; i += T) {
                float z = coord[3 * i + 2]; int s = segment[i], b;
                zs[i] = z;
                sb[i] = (unsigned char)(s & 1);
                CNT_B(i, b);
                if (b != curb) {
                    if (curb >= 0) FLUSH_LDS(curb, lg, lp, lmn, lmx);
                    lg = -INFINITY; lp = INFINITY; lmn = INFINITY; lmx = -INFINITY;
                    curb = b;
                }
                lmn = fminf(lmn, z); lmx = fmaxf(lmx, z);
                if (s == 0) lg = fmaxf(lg, z); else lp = fminf(lp, z);
            }
            if (curb >= 0) FLUSH_LDS(curb, lg, lp, lmn, lmx);
        }
    }
    __syncthreads();
    if (tid < 32) SLOT(ws, blockIdx.x)[tid] = s_stats[tid];   // plain store; boundary = coherence
}

// Pass 2: combine records -> mu (per block, R0-proven); loss from pred (float4)
// + staged z (float4) + staged seg (u32/4pts). Ends with ONE plain store of the
// per-block partial — no atomics, no fences, no done-counter (R4's 54us tail).
__global__ __launch_bounds__(T, 8) void k_loss(
        const float* __restrict__ pred, const int* __restrict__ offset,
        unsigned* __restrict__ ws, int n, int nb) {
    __shared__ unsigned s_comb[32];
    __shared__ float    s_mu[8];
    __shared__ float    s_part[T / 64];
    const int tid = threadIdx.x;
    int roff[8];
    #pragma unroll
    for (int j = 0; j < 8; ++j) roff[j] = (j < nb) ? offset[j] : 0x7FFFFFFF;

    // ---- reduce the NB per-block stat records (coalesced reads + LDS atomics) ----
    if (tid < 32) s_comb[tid] = ident_w(tid);
    __syncthreads();
    {
        const int w = tid & 31, g = tid >> 5;          // 32 groups x 32 words
        unsigned v = ident_w(w);
        #pragma unroll
        for (int j = 0; j < NB / 32; ++j) {
            unsigned u = SLOT((const unsigned*)ws, g * (NB / 32) + j)[w];
            v = (w < 8 || w >= 24) ? max(v, u) : min(v, u);
        }
        if (w < 8 || w >= 24) atomicMax(&s_comb[w], v);
        else                  atomicMin(&s_comb[w], v);
    }
    __syncthreads();
    if (tid < 8) {
        unsigned ug = s_comb[tid], up = s_comb[8 + tid];
        float g = dec_f(ug), p = dec_f(up);
        if (ug == ENC_NEG_INF) g = dec_f(s_comb[16 + tid]);  // no ground -> z.min
        if (up == ENC_POS_INF) p = dec_f(s_comb[24 + tid]);  // no plant  -> z.max
        s_mu[tid] = g + (p - g) * 0.5f;
    }
    __syncthreads();

    int chunk = (n + (int)gridDim.x - 1) / (int)gridDim.x;
    chunk = (chunk + 3) & ~3;
    const int start = blockIdx.x * chunk;
    const int end   = min(n, start + chunk);

    const float*         zs  = (const float*)(ws + ZOFF_W);
    const unsigned char* sbB = (const unsigned char*)(ws + SOFF_W);

    float lsum = 0.0f;
    if (start < end) {
        int ba = 0, bb = 0;
        #pragma unroll
        for (int j = 0; j < 8; ++j) { ba += (start >= roff[j]); bb += ((end - 1) >= roff[j]); }

        if (ba == bb && ((end - start) % (4 * T) == 0)) {
            const float mu = s_mu[ba];
            const float4*   p4 = (const float4*)pred;
            const float4*   z4 = (const float4*)zs;
            const unsigned* sw = (const unsigned*)sbB;
            for (int p0 = start; p0 < end; p0 += 4 * T) {
                const int q = (p0 >> 2) + tid;       // 4-pt group index
                float4 pa = p4[2 * q + 0];           // p0x p0y p1x p1y
                float4 pb = p4[2 * q + 1];           // p2x p2y p3x p3y
                float4 zz = z4[q];
                unsigned s = sw[q];
                lsum += point_loss(pa.x, pa.y, (int)( s        & 1u), zz.x, mu);
                lsum += point_loss(pa.z, pa.w, (int)((s >>  8) & 1u), zz.y, mu);
                lsum += point_loss(pb.x, pb.y, (int)((s >> 16) & 1u), zz.z, mu);
                lsum += point_loss(pb.z, pb.w, (int)((s >> 24) & 1u), zz.w, mu);
            }
        } else {
            const float2* pred2 = (const float2*)pred;
            for (int i = start + tid; i < end; i += T) {
                int b; CNT_B(i, b);
                float2 pp = pred2[i];
                lsum += point_loss(pp.x, pp.y, (int)sbB[i], zs[i], s_mu[b]);
            }
        }
    }

    #pragma unroll
    for (int off = 32; off > 0; off >>= 1) lsum += __shfl_down(lsum, off, 64);
    if ((tid & 63) == 0) s_part[tid >> 6] = lsum;
    __syncthreads();
    if (tid == 0) {
        float t = 0.0f;
        #pragma unroll
        for (int wv = 0; wv < T / 64; ++wv) t += s_part[wv];
        ((float*)(ws + PART_W))[blockIdx.x] = t;   // private slot, plain store
    }
}

// Pass 3: one tiny block sums the NB partials in double and writes the mean.
__global__ __launch_bounds__(NB) void k_final(
        const unsigned* __restrict__ ws, float* __restrict__ out, int n) {
    __shared__ float sp[NB];
    const int tid = threadIdx.x;
    sp[tid] = ((const float*)(ws + PART_W))[tid];
    __syncthreads();
    if (tid == 0) {
        double v = 0.0;
        for (int i = 0; i < NB; ++i) v += (double)sp[i];
        out[0] = (float)(v / (double)n);
    }
}

extern "C" void kernel_launch(void* const* d_in, const int* in_sizes, int n_in,
                              void* d_out, int out_size, void* d_ws, size_t ws_size,
                              hipStream_t stream) {
    const float* pred    = (const float*)d_in[0];
    const float* coord   = (const float*)d_in[1];
    const int*   segment = (const int*)d_in[2];
    const int*   offset  = (const int*)d_in[3];
    const int n  = in_sizes[2];
    const int nb = in_sizes[3];
    unsigned* ws = (unsigned*)d_ws;

    hipLaunchKernelGGL(k_stats, dim3(NB), dim3(T), 0, stream,
                       coord, segment, offset, ws, n, nb);
    hipLaunchKernelGGL(k_loss, dim3(NB), dim3(T), 0, stream,
                       pred, offset, ws, n, nb);
    hipLaunchKernelGGL(k_final, dim3(1), dim3(NB), 0, stream,
                       ws, (float*)d_out, n);
}